// Round 4
// baseline (411.015 us; speedup 1.0000x reference)
//
#include <hip/hip_runtime.h>

// Reference collapses (softmax over size-1 axis == 1; reshapes are identity):
//   out = relu(x @ (gamma*W3 + W4)^T),  x:(B,20), fused M:(200,20)
// Memory floor: 210 MB out write + 21 MB x read => ~37 us @ 6.3 TB/s.
//
// R3 lesson: thread=row direct stores (16 B/lane at 800 B stride) gave 1.6x
// write amplification (WRITE 334 MB) and a store-path bottleneck. R4: same
// compute mapping (x in regs, wave-uniform weights via scalar loads), but
// outputs staged in LDS and written out lane-consecutive (full-line stores).

#define BATCH    262144
#define DICT     20
#define COLS     200                 // NUM_HEADS * DICT
#define NTHREADS 256
#define RPB      64                  // rows per block
#define NBLOCKS  (BATCH / RPB)       // 4096
#define STRIDE2  101                 // stage row stride in float2 (pad +1 -> conflict-free b64)

__global__ __launch_bounds__(NTHREADS)
void attn_collapsed_kernel(const float* __restrict__ x,
                           const float* __restrict__ W3,
                           const float* __restrict__ W4,
                           const float* __restrict__ gamma,
                           float* __restrict__ out)
{
    __shared__ float2 stage[RPB * STRIDE2];   // 51,712 B -> 3 blocks/CU

    const int t   = threadIdx.x;
    const int row = t & 63;                              // lane = local row
    const int seg = __builtin_amdgcn_readfirstlane(t >> 6); // 0..3, wave-uniform (SGPR)
    const float g = gamma[0];

    // x row -> 20 VGPRs, loaded once.
    const int grow = blockIdx.x * RPB + row;
    float4 xv[5];
    {
        const float4* xr = (const float4*)(x + grow * DICT);
#pragma unroll
        for (int i = 0; i < 5; ++i) xv[i] = xr[i];
    }

    // Phase A: this thread computes cols [seg*50, seg*50+50) of its row.
    // Weight pointers are wave-uniform (seg in SGPR) -> scalar s_load path;
    // gamma-fusion recomputed on the fly (weights are 32 KB, fully cached).
    const float4* w3 = (const float4*)(W3 + seg * 50 * DICT);  // 5 float4 per col
    const float4* w4 = (const float4*)(W4 + seg * 50 * DICT);
    float2* srow = &stage[row * STRIDE2 + seg * 25];

#pragma unroll 5
    for (int c = 0; c < 25; ++c) {
        float a0 = 0.f, a1 = 0.f;
#pragma unroll
        for (int k = 0; k < 5; ++k) {
            float4 u3 = w3[(2 * c) * 5 + k];
            float4 u4 = w4[(2 * c) * 5 + k];
            a0 = fmaf(fmaf(g, u3.x, u4.x), xv[k].x, a0);
            a0 = fmaf(fmaf(g, u3.y, u4.y), xv[k].y, a0);
            a0 = fmaf(fmaf(g, u3.z, u4.z), xv[k].z, a0);
            a0 = fmaf(fmaf(g, u3.w, u4.w), xv[k].w, a0);
            float4 v3 = w3[(2 * c + 1) * 5 + k];
            float4 v4 = w4[(2 * c + 1) * 5 + k];
            a1 = fmaf(fmaf(g, v3.x, v4.x), xv[k].x, a1);
            a1 = fmaf(fmaf(g, v3.y, v4.y), xv[k].y, a1);
            a1 = fmaf(fmaf(g, v3.z, v4.z), xv[k].z, a1);
            a1 = fmaf(fmaf(g, v3.w, v4.w), xv[k].w, a1);
        }
        float2 r;
        r.x = fmaxf(a0, 0.f);
        r.y = fmaxf(a1, 0.f);
        srow[c] = r;                 // ds_write_b64, stride 808 B -> bank-uniform
    }
    __syncthreads();

    // Phase B: cooperative lane-consecutive store of the 64x200 tile.
    // 512 B contiguous per wave-instr -> full 64 B lines, no amplification.
    float2* out2 = (float2*)out + (size_t)blockIdx.x * (RPB * COLS / 2);
#pragma unroll
    for (int i = 0; i < 25; ++i) {
        const int h   = t + i * NTHREADS;    // 0..6399 flat float2 index in tile
        const int r   = h / 100;             // magic-mul
        const int rem = h - r * 100;
        out2[h] = stage[r * STRIDE2 + rem];  // LDS reads lane-consecutive
    }
}

extern "C" void kernel_launch(void* const* d_in, const int* in_sizes, int n_in,
                              void* d_out, int out_size, void* d_ws, size_t ws_size,
                              hipStream_t stream) {
    const float* x     = (const float*)d_in[0];
    // d_in[1] = W1, d_in[2] = W2 : mathematically unused (softmax over size-1 axis)
    const float* W3    = (const float*)d_in[3];
    const float* W4    = (const float*)d_in[4];
    const float* gamma = (const float*)d_in[5];
    float* out = (float*)d_out;

    attn_collapsed_kernel<<<NBLOCKS, NTHREADS, 0, stream>>>(x, W3, W4, gamma, out);
}

// Round 5
// 318.707 us; speedup vs baseline: 1.2896x; 1.2896x over previous
//
#include <hip/hip_runtime.h>

// Reference collapses (softmax over size-1 axis == 1; reshapes are identity):
//   out = relu(x @ (gamma*W3 + W4)^T),  x:(B,20), fused M:(200,20)
// Memory floor: 210 MB out write + 21 MB x read => ~37 us @ 6.3 TB/s.
//
// R4 lesson: LDS-transpose fixed write amplification but doubled VALU work
// (in-loop fusion + 2-SGPR-operand v_movs) and serialized phases -> 232 us.
// R2's structure already had PERFECT traffic (WRITE exactly 204,800 KB,
// FETCH 20 MB); it was latency-bound (1 exposed x-load chain per iter).
// R5 = R2 + direct row iteration (no divide) + manual 4x unroll: 20 x-loads
// in flight per wave before the FMA block, stores fire-and-forget.

#define BATCH    262144
#define DICT     20
#define COLS     200                  // NUM_HEADS * DICT
#define NTHREADS 256
#define NBLOCKS  3200                 // 819,200 threads
#define RSTRIDE  8192                 // row stride per iteration (819200/100)
#define ITERS    32                   // 262144 / 8192, exact — no tail
#define UNROLL   4

__global__ __launch_bounds__(NTHREADS)
void attn_collapsed_kernel(const float* __restrict__ x,
                           const float* __restrict__ W3,
                           const float* __restrict__ W4,
                           const float* __restrict__ gamma,
                           float* __restrict__ out)
{
    const int tid = blockIdx.x * NTHREADS + threadIdx.x;
    const int j2  = tid % 100;        // fixed column pair: 2*j2, 2*j2+1
    const int r0  = tid / 100;        // starting row; rows r0 + i*8192
    const float g = gamma[0];

    // Fused weights for the 2 owned columns -> 40 VGPRs (R2-proven, no spill).
    float4 m0[5], m1[5];
    {
        const float4* w3a = (const float4*)(W3 + (2 * j2 + 0) * DICT);
        const float4* w4a = (const float4*)(W4 + (2 * j2 + 0) * DICT);
        const float4* w3b = (const float4*)(W3 + (2 * j2 + 1) * DICT);
        const float4* w4b = (const float4*)(W4 + (2 * j2 + 1) * DICT);
#pragma unroll
        for (int i = 0; i < 5; ++i) {
            float4 a = w3a[i], b = w4a[i];
            m0[i].x = fmaf(g, a.x, b.x);
            m0[i].y = fmaf(g, a.y, b.y);
            m0[i].z = fmaf(g, a.z, b.z);
            m0[i].w = fmaf(g, a.w, b.w);
            a = w3b[i]; b = w4b[i];
            m1[i].x = fmaf(g, a.x, b.x);
            m1[i].y = fmaf(g, a.y, b.y);
            m1[i].z = fmaf(g, a.z, b.z);
            m1[i].w = fmaf(g, a.w, b.w);
        }
    }

    float2* out2 = (float2*)out;

    for (int i = 0; i < ITERS; i += UNROLL) {
        // 1) Issue all x-row loads for 4 independent iterations (20 loads
        //    in flight; lanes 0..99 share a row -> L1 broadcast after the
        //    first HBM touch).
        float4 xv[UNROLL][5];
#pragma unroll
        for (int u = 0; u < UNROLL; ++u) {
            const int r = r0 + (i + u) * RSTRIDE;
            const float4* xr = (const float4*)(x + r * DICT);
#pragma unroll
            for (int k = 0; k < 5; ++k) xv[u][k] = xr[k];
        }

        // 2) FMA blocks + fire-and-forget stores (lane-consecutive:
        //    out2 index = tid + (i+u)*819200 -> 512 B/wave contiguous).
#pragma unroll
        for (int u = 0; u < UNROLL; ++u) {
            float ax = 0.f, ay = 0.f;
#pragma unroll
            for (int k = 0; k < 5; ++k) {
                const float4 xx = xv[u][k];
                ax = fmaf(xx.x, m0[k].x, ax);
                ax = fmaf(xx.y, m0[k].y, ax);
                ax = fmaf(xx.z, m0[k].z, ax);
                ax = fmaf(xx.w, m0[k].w, ax);
                ay = fmaf(xx.x, m1[k].x, ay);
                ay = fmaf(xx.y, m1[k].y, ay);
                ay = fmaf(xx.z, m1[k].z, ay);
                ay = fmaf(xx.w, m1[k].w, ay);
            }
            float2 res;
            res.x = fmaxf(ax, 0.f);
            res.y = fmaxf(ay, 0.f);
            const int r = r0 + (i + u) * RSTRIDE;
            out2[r * 100 + j2] = res;
        }
    }
}

extern "C" void kernel_launch(void* const* d_in, const int* in_sizes, int n_in,
                              void* d_out, int out_size, void* d_ws, size_t ws_size,
                              hipStream_t stream) {
    const float* x     = (const float*)d_in[0];
    // d_in[1] = W1, d_in[2] = W2 : mathematically unused (softmax over size-1 axis)
    const float* W3    = (const float*)d_in[3];
    const float* W4    = (const float*)d_in[4];
    const float* gamma = (const float*)d_in[5];
    float* out = (float*)d_out;

    attn_collapsed_kernel<<<NBLOCKS, NTHREADS, 0, stream>>>(x, W3, W4, gamma, out);
}